// Round 5
// baseline (1422.854 us; speedup 1.0000x reference)
//
#include <hip/hip_runtime.h>
#include <hip/hip_bf16.h>

// Elman RNN: SEQ=2048, BATCH=64, IN=HID=256, fp32 in/out.
// SINGLE kernel, 64 blocks (one per batch), fully self-contained:
//   - scan structure = proven R1 (883 µs): W_hh in VGPRs, broadcast-h MFMA
//     matvec, dual accumulator chains, per-step raw barrier (lgkm only),
//     direct nontemporal fp32 out stores.
//   - input projection FUSED per block: x rows for the NEXT chunk are
//     staged (1KB/step, coalesced, software-pipelined 1 step ahead) into a
//     padded LDS tile; at each chunk boundary a 128-MFMA/wave prep GEMM
//     (x_tile · W_ih^T + bias, W_ih resident in VGPRs) writes the next
//     chunk's xp straight into the xl LDS buffer. xp never touches HBM:
//     no workspace, no producer blocks, no cross-block fences.

typedef short          bfrag8 __attribute__((ext_vector_type(8)));  // 8 bf16 (4 VGPRs)
typedef float          f4     __attribute__((ext_vector_type(4)));
typedef unsigned short us4    __attribute__((ext_vector_type(4)));
typedef unsigned int   ui4    __attribute__((ext_vector_type(4)));

#define HPAD 264   // row pad (shorts) for the staged x tile (bank-conflict break)
#define CH2  64    // time-steps per chunk

static __device__ __forceinline__ unsigned short f2bf(float f) {
    union { float f; unsigned u; } v; v.f = f;
    unsigned r = v.u + 0x7FFFu + ((v.u >> 16) & 1u);   // RNE truncate
    return (unsigned short)(r >> 16);
}
static __device__ __forceinline__ float bf2f(unsigned short s) {
    union { unsigned u; float f; } v; v.u = ((unsigned)s) << 16;
    return v.f;
}

__global__ __launch_bounds__(256, 1) void rnn_fused(
    const float* __restrict__ x, const float* __restrict__ Wih,
    const float* __restrict__ Whh, const float* __restrict__ bih,
    const float* __restrict__ bhh, float* __restrict__ out)
{
    __shared__ unsigned short xl[2][CH2 * 256];              // xp chunks (bf16) 64 KB
    __shared__ __align__(16) unsigned short hrow[2][256];    // ping-pong h (bf16)
    __shared__ __align__(16) unsigned short xstage[64 * HPAD]; // next-chunk x (bf16) 33 KB

    const int tid  = threadIdx.x;
    const int wave = tid >> 6;
    const int lane = tid & 63;
    const int l15  = lane & 15;
    const int quad = lane >> 4;
    const int b    = blockIdx.x;

    if (tid < 32) ((ui4*)&hrow[0][0])[tid] = (ui4){0u, 0u, 0u, 0u};  // h0 = 0

    // W_hh fragments: B[k][n] = W_hh[n][k], resident in VGPRs for the whole scan
    bfrag8 Bf[4][8];
    #pragma unroll
    for (int nt = 0; nt < 4; ++nt) {
        const int n = wave * 64 + nt * 16 + l15;
        #pragma unroll
        for (int kt = 0; kt < 8; ++kt) {
            const float* wp = Whh + n * 256 + kt * 32 + quad * 8;
            const f4 wa = *(const f4*)wp;
            const f4 wb = *(const f4*)(wp + 4);
            union { bfrag8 v; unsigned short s[8]; } w;
            #pragma unroll
            for (int j = 0; j < 4; ++j) { w.s[j] = f2bf(wa[j]); w.s[4 + j] = f2bf(wb[j]); }
            Bf[nt][kt] = w.v;
        }
    }
    // W_ih fragments + fused bias, also resident (prep GEMM operand)
    bfrag8 Wf[4][8];
    float  bs[4];
    #pragma unroll
    for (int nt = 0; nt < 4; ++nt) {
        const int n = wave * 64 + nt * 16 + l15;
        bs[nt] = bih[n] + bhh[n];
        #pragma unroll
        for (int kt = 0; kt < 8; ++kt) {
            const float* wp = Wih + n * 256 + kt * 32 + quad * 8;
            const f4 wa = *(const f4*)wp;
            const f4 wb = *(const f4*)(wp + 4);
            union { bfrag8 v; unsigned short s[8]; } w;
            #pragma unroll
            for (int j = 0; j < 4; ++j) { w.s[j] = f2bf(wa[j]); w.s[4 + j] = f2bf(wb[j]); }
            Wf[nt][kt] = w.v;
        }
    }

    // prep GEMM: xstage (64x256 bf16) · W_ih^T + bias -> dst[s*256+n] (bf16)
    auto prep = [&](unsigned short* dst) {
        f4 pacc[4][4];
        #pragma unroll
        for (int mt = 0; mt < 4; ++mt)
            #pragma unroll
            for (int nt = 0; nt < 4; ++nt)
                pacc[mt][nt] = (f4){0.f, 0.f, 0.f, 0.f};
        #pragma unroll
        for (int kt = 0; kt < 8; ++kt) {
            bfrag8 Paf[4];
            #pragma unroll
            for (int mt = 0; mt < 4; ++mt)
                Paf[mt] = *(const bfrag8*)(&xstage[(mt * 16 + l15) * HPAD + kt * 32 + quad * 8]);
            #pragma unroll
            for (int mt = 0; mt < 4; ++mt)
                #pragma unroll
                for (int nt = 0; nt < 4; ++nt)
                    pacc[mt][nt] = __builtin_amdgcn_mfma_f32_16x16x32_bf16(
                        Paf[mt], Wf[nt][kt], pacc[mt][nt], 0, 0, 0);
        }
        #pragma unroll
        for (int mt = 0; mt < 4; ++mt)
            #pragma unroll
            for (int r = 0; r < 4; ++r) {
                const int row = mt * 16 + quad * 4 + r;
                #pragma unroll
                for (int nt = 0; nt < 4; ++nt)
                    dst[row * 256 + wave * 64 + nt * 16 + l15] = f2bf(pacc[mt][nt][r] + bs[nt]);
            }
    };

    // ---- upfront: stage chunk 0's x rows, prep xl[0]
    {
        const int rb = tid >> 6;
        const int cb = (tid & 63) * 4;
        #pragma unroll
        for (int it = 0; it < 16; ++it) {
            const int r = it * 4 + rb;           // r == t for chunk 0
            const f4 v = *(const f4*)(x + ((long)r * 64 + b) * 256 + cb);
            us4 o;
            o[0] = f2bf(v[0]); o[1] = f2bf(v[1]);
            o[2] = f2bf(v[2]); o[3] = f2bf(v[3]);
            *(us4*)(&xstage[r * HPAD + cb]) = o;
        }
    }
    __syncthreads();
    prep(&xl[0][0]);
    asm volatile("s_waitcnt lgkmcnt(0)" ::: "memory");
    __builtin_amdgcn_s_barrier();
    asm volatile("" ::: "memory");

    const int abase = quad * 8;                       // A slice: k = quad*8 + j
    const int nsel  = wave * 64 + quad * 16 + l15;    // this lane's output column
    int p = 0;

    for (int c = 0; c < 32; ++c) {
        const unsigned short* xcur = &xl[c & 1][0];
        float* outc = out + (((long)c * CH2) * 64 + b) * 256 + nsel;
        // next chunk's base timestep (c=31 wraps to 0: dummy, never consumed)
        const int tb = ((c + 1) & 31) * 64;

        // software-pipelined x-row staging: load row s+1 while writing row s
        float pend = x[((long)tb * 64 + b) * 256 + tid];

        #pragma unroll 2
        for (int s = 0; s < CH2; ++s) {
            // issue next row's load early (1 dword/lane, coalesced 1KB)
            const float nxt = x[((long)(tb + ((s + 1) & 63)) * 64 + b) * 256 + tid];

            const float xv = bf2f(xcur[s * 256 + nsel]);  // issued early, used late

            // A fragments: pure broadcast of h (all M-rows identical -> all
            // D-rows are valid replicas)
            bfrag8 Af[8];
            const unsigned short* hbp = &hrow[p][0];
            #pragma unroll
            for (int kt = 0; kt < 8; ++kt)
                Af[kt] = *(const bfrag8*)(hbp + abase + kt * 32);

            f4 accA[4], accB[4];
            #pragma unroll
            for (int nt = 0; nt < 4; ++nt) {
                accA[nt] = (f4){0.f, 0.f, 0.f, 0.f};
                accB[nt] = (f4){0.f, 0.f, 0.f, 0.f};
            }
            #pragma unroll
            for (int kt = 0; kt < 4; ++kt)
                #pragma unroll
                for (int nt = 0; nt < 4; ++nt) {
                    accA[nt] = __builtin_amdgcn_mfma_f32_16x16x32_bf16(
                        Af[kt],     Bf[nt][kt],     accA[nt], 0, 0, 0);
                    accB[nt] = __builtin_amdgcn_mfma_f32_16x16x32_bf16(
                        Af[kt + 4], Bf[nt][kt + 4], accB[nt], 0, 0, 0);
                }

            // every quad holds a full replica in reg0; lane uses tile nt==quad
            const float za = (quad == 0) ? accA[0][0] : (quad == 1) ? accA[1][0]
                           : (quad == 2) ? accA[2][0] : accA[3][0];
            const float zb = (quad == 0) ? accB[0][0] : (quad == 1) ? accB[1][0]
                           : (quad == 2) ? accB[2][0] : accB[3][0];
            const float z  = za + zb + xv;

            // tanh(z) = 1 - 2/(exp2(z*2*log2e)+1); |z| small, no clamps
            const float e2 = exp2f(z * 2.885390082f);
            const float hv = 1.f - 2.f * __builtin_amdgcn_rcpf(e2 + 1.f);

            hrow[p ^ 1][nsel] = f2bf(hv);   // h for next step (critical path)

            // fire-and-forget fp32 output store (1KB contiguous per block-step)
            __builtin_nontemporal_store(hv, outc + (long)s * (64 * 256));

            // stage this step's pending x row (for next chunk's prep GEMM)
            xstage[s * HPAD + tid] = f2bf(pend);
            // pend was loaded a full step ago -> VMEM latency already hidden
            p ^= 1;
            asm volatile("s_waitcnt lgkmcnt(0)" ::: "memory");
            __builtin_amdgcn_s_barrier();
            asm volatile("" ::: "memory");
            pend = nxt;
        }

        if (c < 31) {   // uniform branch: build next chunk's xp in LDS
            prep(&xl[(c + 1) & 1][0]);
            asm volatile("s_waitcnt lgkmcnt(0)" ::: "memory");
            __builtin_amdgcn_s_barrier();
            asm volatile("" ::: "memory");
        }
    }
}

extern "C" void kernel_launch(void* const* d_in, const int* in_sizes, int n_in,
                              void* d_out, int out_size, void* d_ws, size_t ws_size,
                              hipStream_t stream) {
    const float* x   = (const float*)d_in[0];
    const float* Wih = (const float*)d_in[1];
    const float* Whh = (const float*)d_in[2];
    const float* bih = (const float*)d_in[3];
    const float* bhh = (const float*)d_in[4];
    float* out = (float*)d_out;
    (void)d_ws; (void)ws_size;   // no workspace needed: xp never leaves LDS

    rnn_fused<<<64, 256, 0, stream>>>(x, Wih, Whh, bih, bhh, out);
}

// Round 6
// 912.835 us; speedup vs baseline: 1.5587x; 1.5587x over previous
//
#include <hip/hip_runtime.h>
#include <hip/hip_bf16.h>

// Elman RNN: SEQ=2048, BATCH=64, IN=HID=256, fp32 in/out.
// Kernel 1: xp[b][t][n] (bf16, d_ws) = x[t]·W_ih^T + b_ih + b_hh. (R1, proven)
// Kernel 2: per-batch serial scan — R1 structure (883 µs) with the recurrent
//           matvec switched bf16 -> i8 MFMA (16x16x64, 2x K):
//           64 -> 32 MFMAs/wave-step and 8 -> 4 A-frag ds_reads. W_hh is
//           quantized once with PER-ROW scales (sw_n = 127/rowmax) into
//           resident VGPR frags; h is quantized rint(h*127) each step
//           (i8 in the LDS broadcast row). i32 accumulation is exact;
//           dequant z = (iA+iB) * (rowmax/127^2) + xv. xp path, tanh,
//           chunk DMA, barriers, out stores: unchanged from R1.

typedef short          bfrag8 __attribute__((ext_vector_type(8)));  // 8 bf16 (4 VGPRs)
typedef int            i32x4  __attribute__((ext_vector_type(4)));  // 16 i8 / 4 i32 acc
typedef float          f4     __attribute__((ext_vector_type(4)));
typedef unsigned short us4    __attribute__((ext_vector_type(4)));
typedef unsigned int   ui4    __attribute__((ext_vector_type(4)));

#define HPAD 264   // row pad (shorts) for the 64-row GEMM tiles
#define CH2  64    // time-steps per xp/out LDS chunk in the scan
#define TPB  8     // timesteps per block in xp_gemm

static __device__ __forceinline__ unsigned short f2bf(float f) {
    union { float f; unsigned u; } v; v.f = f;
    unsigned r = v.u + 0x7FFFu + ((v.u >> 16) & 1u);   // RNE truncate
    return (unsigned short)(r >> 16);
}
static __device__ __forceinline__ float bf2f(unsigned short s) {
    union { unsigned u; float f; } v; v.u = ((unsigned)s) << 16;
    return v.f;
}
static __device__ __forceinline__ void gl2lds16(const unsigned short* g, unsigned short* l) {
    __builtin_amdgcn_global_load_lds(
        (const __attribute__((address_space(1))) void*)g,
        (__attribute__((address_space(3))) void*)l, 16, 0, 0);
}

// ---------------------------------------------------------------- kernel 1
__global__ __launch_bounds__(256) void xp_gemm(
    const float* __restrict__ x, const float* __restrict__ Wih,
    const float* __restrict__ bih, const float* __restrict__ bhh,
    unsigned short* __restrict__ xp)
{
    __shared__ unsigned short xs[64 * HPAD];   // A staging (x tile, bf16)
    __shared__ unsigned short rs[64 * HPAD];   // result staging ([b][n] bf16)
    const int tid  = threadIdx.x;
    const int wave = tid >> 6;
    const int lane = tid & 63;
    const int l15  = lane & 15;
    const int quad = lane >> 4;
    const int t0   = blockIdx.x * TPB;

    // B fragments from W_ih (scattered L2 reads — done ONCE per block):
    // B[k][n] = W_ih[n][k]; lane: n=l15(+tile), k=quad*8+j
    bfrag8 Bf[4][8];
    float  bs[4];
    #pragma unroll
    for (int nt = 0; nt < 4; ++nt) {
        const int n = wave * 64 + nt * 16 + l15;
        bs[nt] = bih[n] + bhh[n];
        #pragma unroll
        for (int kt = 0; kt < 8; ++kt) {
            const float* wp = Wih + n * 256 + kt * 32 + quad * 8;
            const f4 wa = *(const f4*)wp;
            const f4 wb = *(const f4*)(wp + 4);
            union { bfrag8 v; unsigned short s[8]; } u;
            #pragma unroll
            for (int j = 0; j < 4; ++j) { u.s[j] = f2bf(wa[j]); u.s[4 + j] = f2bf(wb[j]); }
            Bf[nt][kt] = u.v;
        }
    }

    for (int tt = 0; tt < TPB; ++tt) {
        const int t = t0 + tt;

        // stage 64x256 fp32 -> bf16 LDS (coalesced dwordx4 reads)
        {
            const int rb = tid >> 6;
            const int cb = (tid & 63) * 4;
            #pragma unroll
            for (int it = 0; it < 16; ++it) {
                const int r = it * 4 + rb;
                const f4 v = *(const f4*)(x + ((long)t * 64 + r) * 256 + cb);
                us4 o;
                o[0] = f2bf(v[0]); o[1] = f2bf(v[1]);
                o[2] = f2bf(v[2]); o[3] = f2bf(v[3]);
                *(us4*)(&xs[r * HPAD + cb]) = o;
            }
        }
        __syncthreads();

        f4 acc[4][4];
        #pragma unroll
        for (int mt = 0; mt < 4; ++mt)
            #pragma unroll
            for (int nt = 0; nt < 4; ++nt)
                acc[mt][nt] = (f4){0.f, 0.f, 0.f, 0.f};

        #pragma unroll
        for (int kt = 0; kt < 8; ++kt) {
            bfrag8 Af[4];
            #pragma unroll
            for (int mt = 0; mt < 4; ++mt)
                Af[mt] = *(const bfrag8*)(&xs[(mt * 16 + l15) * HPAD + kt * 32 + quad * 8]);
            #pragma unroll
            for (int mt = 0; mt < 4; ++mt)
                #pragma unroll
                for (int nt = 0; nt < 4; ++nt)
                    acc[mt][nt] = __builtin_amdgcn_mfma_f32_16x16x32_bf16(
                        Af[mt], Bf[nt][kt], acc[mt][nt], 0, 0, 0);
        }
        __syncthreads();   // all xs reads done

        // stage results (bf16, +bias) into rs as [b][n]
        #pragma unroll
        for (int mt = 0; mt < 4; ++mt)
            #pragma unroll
            for (int r = 0; r < 4; ++r) {
                const int bb = mt * 16 + quad * 4 + r;
                #pragma unroll
                for (int nt = 0; nt < 4; ++nt)
                    rs[bb * HPAD + wave * 64 + nt * 16 + l15] = f2bf(acc[mt][nt][r] + bs[nt]);
            }
        __syncthreads();

        // coalesced 16B stores: xp[(b*2048 + t)*256 + n]
        #pragma unroll
        for (int i = 0; i < 8; ++i) {
            const int chunk = i * 256 + tid;
            const int bb  = chunk >> 5;
            const int seg = chunk & 31;
            const ui4 v = *(const ui4*)(&rs[bb * HPAD + seg * 8]);
            *(ui4*)(xp + ((long)bb * 2048 + t) * 256 + seg * 8) = v;
        }
        __syncthreads();   // store-reads of rs done before next iter's rs write
    }
}

// ---------------------------------------------------------------- kernel 2
__global__ __launch_bounds__(256, 1) void rnn_scan(
    const unsigned short* __restrict__ xp, const float* __restrict__ Whh,
    float* __restrict__ out)
{
    __shared__ unsigned short xl[2][CH2 * 256];         // xp chunks (bf16)  64 KB
    __shared__ __align__(16) signed char hrow[2][256];  // ping-pong h (i8)

    const int tid  = threadIdx.x;
    const int wave = tid >> 6;
    const int lane = tid & 63;
    const int l15  = lane & 15;
    const int quad = lane >> 4;
    const int b    = blockIdx.x;

    if (tid < 16) ((ui4*)&hrow[0][0])[tid] = (ui4){0u, 0u, 0u, 0u};  // h0 = 0

    // W_hh quantized to i8 frags with PER-ROW scales, resident in VGPRs.
    // B[k][n] = W_hh[n][k]; lane holds, for k-tile kt (K=64 each),
    // bytes k = kt*64 + quad*16 + j (j=0..15). A uses the same (lane,j)->k
    // map, so any k-permutation cancels in the MFMA dot product.
    i32x4 Bfi[4][4];
    float dsc[4];   // dequant scale per nt-row owned by this lane
    #pragma unroll
    for (int nt = 0; nt < 4; ++nt) {
        const int n = wave * 64 + nt * 16 + l15;
        float wv[64];
        #pragma unroll
        for (int kt = 0; kt < 4; ++kt)
            #pragma unroll
            for (int m4 = 0; m4 < 4; ++m4) {
                const f4 v = *(const f4*)(Whh + n * 256 + kt * 64 + quad * 16 + m4 * 4);
                wv[kt * 16 + m4 * 4 + 0] = v[0];
                wv[kt * 16 + m4 * 4 + 1] = v[1];
                wv[kt * 16 + m4 * 4 + 2] = v[2];
                wv[kt * 16 + m4 * 4 + 3] = v[3];
            }
        float pm = 0.f;
        #pragma unroll
        for (int j = 0; j < 64; ++j) pm = fmaxf(pm, fabsf(wv[j]));
        // row max across the 4 quads holding this row's k-ranges
        pm = fmaxf(pm, __shfl_xor(pm, 16));
        pm = fmaxf(pm, __shfl_xor(pm, 32));
        const float sw = 127.f / pm;
        dsc[nt] = pm * (1.f / (127.f * 127.f));
        #pragma unroll
        for (int kt = 0; kt < 4; ++kt) {
            union { i32x4 v; signed char c[16]; } pk;
            #pragma unroll
            for (int j = 0; j < 16; ++j)
                pk.c[j] = (signed char)__float2int_rn(wv[kt * 16 + j] * sw);
            Bfi[nt][kt] = pk.v;
        }
    }

    const unsigned short* xpb = xp + (long)b * 2048 * 256;

    // preload chunk 0 -> buf 0 (direct global->LDS DMA, lane-contiguous)
    #pragma unroll
    for (int i = 0; i < 8; ++i)
        gl2lds16(xpb + i * 2048 + tid * 8, &xl[0][i * 2048 + wave * 512]);

    const int nsel = wave * 64 + quad * 16 + l15;    // this lane's output column
    const float dsel = (quad == 0) ? dsc[0] : (quad == 1) ? dsc[1]
                     : (quad == 2) ? dsc[2] : dsc[3];
    int p = 0;

    // h0-zero LDS writes visible before the first step barrier
    asm volatile("s_waitcnt lgkmcnt(0)" ::: "memory");

    for (int c = 0; c < 32; ++c) {
        // issue next chunk into the other buffer; stays in flight across the
        // whole chunk (counted vmcnt, never drained to 0 mid-scan).
        const int cn = (c < 31) ? c + 1 : 31;
        #pragma unroll
        for (int i = 0; i < 8; ++i)
            gl2lds16(xpb + (long)cn * (CH2 * 256) + i * 2048 + tid * 8,
                     &xl[(c + 1) & 1][i * 2048 + wave * 512]);
        // keep the 8 newest (next chunk) outstanding; this chunk's DMA retired
        asm volatile("s_waitcnt vmcnt(8)" ::: "memory");
        __builtin_amdgcn_s_barrier();
        asm volatile("" ::: "memory");

        const unsigned short* xcur = &xl[c & 1][0];
        float* outc = out + (((long)c * CH2) * 64 + b) * 256 + nsel;

        #pragma unroll 2
        for (int s = 0; s < CH2; ++s) {
            const float xv = bf2f(xcur[s * 256 + nsel]);  // issued early, used late

            // A fragments: broadcast of the i8 h row (all M-rows identical ->
            // all D-rows are valid replicas). 4 reads (K=64 per tile).
            i32x4 af[4];
            const signed char* hbp = &hrow[p][0];
            #pragma unroll
            for (int kt = 0; kt < 4; ++kt)
                af[kt] = *(const i32x4*)(hbp + kt * 64 + quad * 16);

            i32x4 accA[4], accB[4];
            #pragma unroll
            for (int nt = 0; nt < 4; ++nt) {
                accA[nt] = (i32x4){0, 0, 0, 0};
                accB[nt] = (i32x4){0, 0, 0, 0};
            }
            #pragma unroll
            for (int kt = 0; kt < 2; ++kt)
                #pragma unroll
                for (int nt = 0; nt < 4; ++nt) {
                    accA[nt] = __builtin_amdgcn_mfma_i32_16x16x64_i8(
                        af[kt],     Bfi[nt][kt],     accA[nt], 0, 0, 0);
                    accB[nt] = __builtin_amdgcn_mfma_i32_16x16x64_i8(
                        af[kt + 2], Bfi[nt][kt + 2], accB[nt], 0, 0, 0);
                }

            // every quad holds a full replica in reg0; lane uses tile nt==quad
            const int ia = (quad == 0) ? accA[0][0] : (quad == 1) ? accA[1][0]
                         : (quad == 2) ? accA[2][0] : accA[3][0];
            const int ib = (quad == 0) ? accB[0][0] : (quad == 1) ? accB[1][0]
                         : (quad == 2) ? accB[2][0] : accB[3][0];
            const float z = (float)(ia + ib) * dsel + xv;   // i32 sum is exact

            // tanh(z) = 1 - 2/(exp2(z*2*log2e)+1); |z| small, no clamps
            const float e2 = exp2f(z * 2.885390082f);
            const float hv = 1.f - 2.f * __builtin_amdgcn_rcpf(e2 + 1.f);

            // h for next step, quantized i8 (|hv|<1 -> fits in [-127,127])
            hrow[p ^ 1][nsel] = (signed char)__float2int_rn(hv * 127.f);

            // fire-and-forget fp32 output store (1KB contiguous per block-step)
            __builtin_nontemporal_store(hv, outc + (long)s * (64 * 256));

            p ^= 1;
            // raw barrier: drain LDS ops only — global stores and next-chunk
            // DMA remain outstanding.
            asm volatile("s_waitcnt lgkmcnt(0)" ::: "memory");
            __builtin_amdgcn_s_barrier();
            asm volatile("" ::: "memory");
        }
    }
}

extern "C" void kernel_launch(void* const* d_in, const int* in_sizes, int n_in,
                              void* d_out, int out_size, void* d_ws, size_t ws_size,
                              hipStream_t stream) {
    const float* x   = (const float*)d_in[0];
    const float* Wih = (const float*)d_in[1];
    const float* Whh = (const float*)d_in[2];
    const float* bih = (const float*)d_in[3];
    const float* bhh = (const float*)d_in[4];
    float* out = (float*)d_out;
    unsigned short* xpw = (unsigned short*)d_ws;   // 2048*64*256 bf16 = 64 MiB

    if (ws_size < (size_t)2048 * 64 * 256 * 2) return;  // fail visibly, don't corrupt

    xp_gemm<<<2048 / TPB, 256, 0, stream>>>(x, Wih, bih, bhh, xpw);
    rnn_scan<<<64, 256, 0, stream>>>(xpw, Whh, out);
}